// Round 1
// baseline (1014.496 us; speedup 1.0000x reference)
//
#include <hip/hip_runtime.h>

// ---------------------------------------------------------------------------
// MemN2N temporal layer, MEM=64 BATCH=32 L=64 E=1024 H=1024 HOPS=3, fp32.
//
// Key algebra: with S[j,b,e] = sum_l inputs[j,b,l,e],
//   s[b,j] = sum_e S[j,b,e]*w[b,e] + sum_h TA[j,h]*u[b,h],  w[b,e]=sum_h A[e,h]u[b,h]
//   o[b,h] = sum_e r[b,e]*C[e,h] + sum_j p[b,j]*TC[j,h],    r[b,e]=sum_j p[b,j]S[j,b,e]
// so the 2048x1024x1024 GEMMs for m,c are never materialized; per-hop cost is
// two skinny fp32 GEMVs. fp32 throughout keeps softmax-argmax stable
// (bf16 MFMA would perturb s by ~13 vs near-one-hot logits sigma~2048).
// ---------------------------------------------------------------------------

#define NMEM 64
#define NBATCH 32
#define NL 64
#define NE 1024
#define NH 1024
#define NEP 1088   /* NE + NMEM: A' = [A ; TA] */
#define NHOPS 3

// workspace float offsets (all multiples of 4 -> 16B aligned)
#define OFF_S   0u                          /* S: 2048 x 1024           */
#define OFF_QS  (2048u*1024u)               /* qs: 32 x 1024            */
#define OFF_W   (OFF_QS + 32u*1024u)        /* w: 32 x 1088             */
#define OFF_P   (OFF_W + 32u*1088u)         /* p: 32 x 64               */
#define OFF_R   (OFF_P + 32u*64u)           /* r: 32 x 1024             */
#define OFF_AT  (OFF_R + 32u*1024u)         /* At: 1024 x 1088 (A' ^T)  */

// ---------------------------------------------------------------------------
// K_reduce: blocks 0..2047   : S[row,:] = sum_l inputs[row, l, :]   (512 MiB read)
//           blocks 2048..2079: qs[b,:] = sum_l questions[b,l,:]; zero u[b,:], w[b,:]
//           blocks 2080..2351: At[h,e'] = A'[e',h]  (LDS tile transpose)
// ---------------------------------------------------------------------------
__global__ __launch_bounds__(256) void k_reduce(
    const float* __restrict__ inputs, const float* __restrict__ questions,
    const float* __restrict__ A, const float* __restrict__ TA,
    float* __restrict__ S, float* __restrict__ qs,
    float* __restrict__ w, float* __restrict__ u, float* __restrict__ At) {
  const int blk = blockIdx.x, t = threadIdx.x;
  __shared__ float tile[64][65];

  if (blk < 2048) {
    const float4* base = (const float4*)(inputs + (size_t)blk * (NL * NE));
    float4 acc = make_float4(0.f, 0.f, 0.f, 0.f);
#pragma unroll 8
    for (int l = 0; l < NL; ++l) {
      float4 v = base[l * (NE / 4) + t];
      acc.x += v.x; acc.y += v.y; acc.z += v.z; acc.w += v.w;
    }
    ((float4*)(S + (size_t)blk * NE))[t] = acc;
  } else if (blk < 2080) {
    const int b = blk - 2048;
    const float4* base = (const float4*)(questions + (size_t)b * (NL * NE));
    float4 acc = make_float4(0.f, 0.f, 0.f, 0.f);
#pragma unroll 8
    for (int l = 0; l < NL; ++l) {
      float4 v = base[l * (NE / 4) + t];
      acc.x += v.x; acc.y += v.y; acc.z += v.z; acc.w += v.w;
    }
    ((float4*)(qs + (size_t)b * NE))[t] = acc;
    const float4 z = make_float4(0.f, 0.f, 0.f, 0.f);
    ((float4*)(u + (size_t)b * NH))[t] = z;          // u[b, 0..1023] = 0
    ((float4*)(w + (size_t)b * NEP))[t] = z;         // w[b, 0..1023] = 0
    if (t < 16) ((float4*)(w + (size_t)b * NEP))[256 + t] = z;  // w[b,1024..1087]=0
  } else {
    const int idx = blk - 2080;
    const int et = idx % 17;      // e'-tile of 64 (17*64 = 1088)
    const int ht = idx / 17;      // h-tile of 64  (16*64 = 1024)
    const int r0 = t >> 6, c = t & 63;
#pragma unroll
    for (int rr = r0; rr < 64; rr += 4) {
      const int e = et * 64 + rr, h = ht * 64 + c;
      float v = (e < NE) ? A[(size_t)e * NH + h] : TA[(size_t)(e - NE) * NH + h];
      tile[rr][c] = v;
    }
    __syncthreads();
#pragma unroll
    for (int rr = r0; rr < 64; rr += 4) {
      const int h = ht * 64 + rr, e = et * 64 + c;
      At[(size_t)h * NEP + e] = tile[c][rr];
    }
  }
}

// ---------------------------------------------------------------------------
// K_u0: u[b,h] += sum_e qs[b,e] * B[e,h]   (split over e-chunks, atomic)
// grid (4 h-tiles, 4 b-groups of 8, 4 e-chunks of 256), 256 threads
// ---------------------------------------------------------------------------
__global__ __launch_bounds__(256) void k_u0(
    const float* __restrict__ qs, const float* __restrict__ B,
    float* __restrict__ u) {
  const int h = blockIdx.x * 256 + threadIdx.x;
  const int b0 = blockIdx.y * 8;
  const int e0 = blockIdx.z * 256;
  float acc[8] = {0.f, 0.f, 0.f, 0.f, 0.f, 0.f, 0.f, 0.f};
  for (int e = e0; e < e0 + 256; ++e) {
    const float bv = B[(size_t)e * NH + h];
#pragma unroll
    for (int bb = 0; bb < 8; ++bb) acc[bb] += qs[(size_t)(b0 + bb) * NE + e] * bv;
  }
#pragma unroll
  for (int bb = 0; bb < 8; ++bb) atomicAdd(&u[(size_t)(b0 + bb) * NH + h], acc[bb]);
}

// ---------------------------------------------------------------------------
// K_w: w[b,e'] += sum_h u[b,h] * At[h,e']   (A' = [A;TA], w pre-zeroed)
// grid (5 e'-tiles, 4 b-groups, 4 h-chunks), 256 threads; guard e' < 1088
// ---------------------------------------------------------------------------
__global__ __launch_bounds__(256) void k_w(
    const float* __restrict__ At, const float* __restrict__ u,
    float* __restrict__ w) {
  const int ep = blockIdx.x * 256 + threadIdx.x;
  if (ep >= NEP) return;
  const int b0 = blockIdx.y * 8;
  const int h0 = blockIdx.z * 256;
  float acc[8] = {0.f, 0.f, 0.f, 0.f, 0.f, 0.f, 0.f, 0.f};
  for (int h = h0; h < h0 + 256; ++h) {
    const float av = At[(size_t)h * NEP + ep];
#pragma unroll
    for (int bb = 0; bb < 8; ++bb) acc[bb] += u[(size_t)(b0 + bb) * NH + h] * av;
  }
#pragma unroll
  for (int bb = 0; bb < 8; ++bb) atomicAdd(&w[(size_t)(b0 + bb) * NEP + ep], acc[bb]);
}

// ---------------------------------------------------------------------------
// K_sr: per batch b: s_j = S[j,b,:].w[b,:] + w[b,1024+j]; p = softmax(s);
//       r[b,e] = sum_j p_j S[j,b,e]. Re-zeroes w for the next hop.
// grid 32, block 1024 (16 waves)
// ---------------------------------------------------------------------------
__global__ __launch_bounds__(1024) void k_sr(
    const float* __restrict__ S, float* __restrict__ w,
    float* __restrict__ p, float* __restrict__ r) {
  const int b = blockIdx.x, t = threadIdx.x;
  __shared__ float sp[1024];
  __shared__ float lp[64];

  {  // phase A: partial dot products, thread (j = t>>4, g = t&15) does 64 e's
    const int j = t >> 4, g = t & 15;
    const float4* S4 = (const float4*)(S + (size_t)(j * NBATCH + b) * NE + g * 64);
    const float4* w4 = (const float4*)(w + (size_t)b * NEP + g * 64);
    float acc = 0.f;
#pragma unroll
    for (int i = 0; i < 16; ++i) {
      float4 sv = S4[i], wv = w4[i];
      acc += sv.x * wv.x + sv.y * wv.y + sv.z * wv.z + sv.w * wv.w;
    }
    sp[t] = acc;
  }
  __syncthreads();
  if (t < 64) {  // wave 0: finish s_j, softmax
    float s = w[(size_t)b * NEP + NE + t];  // TA.u term
#pragma unroll
    for (int g = 0; g < 16; ++g) s += sp[t * 16 + g];
    float m = s;
#pragma unroll
    for (int off = 32; off > 0; off >>= 1) m = fmaxf(m, __shfl_xor(m, off, 64));
    const float ex = __expf(s - m);
    float l = ex;
#pragma unroll
    for (int off = 32; off > 0; off >>= 1) l += __shfl_xor(l, off, 64);
    const float pv = ex / l;
    lp[t] = pv;
    p[(size_t)b * NMEM + t] = pv;
  }
  __syncthreads();
  {  // phase B: r[b,e], thread e = t
    float acc = 0.f;
#pragma unroll 8
    for (int j = 0; j < NMEM; ++j)
      acc += lp[j] * S[(size_t)(j * NBATCH + b) * NE + t];
    r[(size_t)b * NE + t] = acc;
  }
  // zero w row b for next hop's atomic accumulation (all reads of w are above)
  w[(size_t)b * NEP + t] = 0.f;
  if (t < 64) w[(size_t)b * NEP + NE + t] = 0.f;
}

// ---------------------------------------------------------------------------
// K_o: u[b,h] += sum_e r[b,e]*C[e,h]  (+ sum_j p[b,j]*TC[j,h] on e-chunk 0)
// grid (4 h-tiles, 4 b-groups, 4 e-chunks), 256 threads
// ---------------------------------------------------------------------------
__global__ __launch_bounds__(256) void k_o(
    const float* __restrict__ C, const float* __restrict__ TC,
    const float* __restrict__ r, const float* __restrict__ p,
    float* __restrict__ u) {
  const int h = blockIdx.x * 256 + threadIdx.x;
  const int b0 = blockIdx.y * 8;
  const int e0 = blockIdx.z * 256;
  float acc[8] = {0.f, 0.f, 0.f, 0.f, 0.f, 0.f, 0.f, 0.f};
  for (int e = e0; e < e0 + 256; ++e) {
    const float cv = C[(size_t)e * NH + h];
#pragma unroll
    for (int bb = 0; bb < 8; ++bb) acc[bb] += r[(size_t)(b0 + bb) * NE + e] * cv;
  }
  if (blockIdx.z == 0) {
    for (int j = 0; j < NMEM; ++j) {
      const float tcv = TC[(size_t)j * NH + h];
#pragma unroll
      for (int bb = 0; bb < 8; ++bb) acc[bb] += p[(size_t)(b0 + bb) * NMEM + j] * tcv;
    }
  }
#pragma unroll
  for (int bb = 0; bb < 8; ++bb) atomicAdd(&u[(size_t)(b0 + bb) * NH + h], acc[bb]);
}

// ---------------------------------------------------------------------------
extern "C" void kernel_launch(void* const* d_in, const int* in_sizes, int n_in,
                              void* d_out, int out_size, void* d_ws, size_t ws_size,
                              hipStream_t stream) {
  (void)in_sizes; (void)n_in; (void)out_size; (void)ws_size;
  const float* inputs    = (const float*)d_in[0];
  const float* questions = (const float*)d_in[1];
  const float* A         = (const float*)d_in[2];
  const float* C         = (const float*)d_in[3];
  const float* B         = (const float*)d_in[4];
  const float* TA        = (const float*)d_in[5];
  const float* TC        = (const float*)d_in[6];
  float* u  = (float*)d_out;
  float* ws = (float*)d_ws;
  float* S  = ws + OFF_S;
  float* qs = ws + OFF_QS;
  float* w  = ws + OFF_W;
  float* p  = ws + OFF_P;
  float* r  = ws + OFF_R;
  float* At = ws + OFF_AT;

  // S + qs + zero(u,w) + transpose A' -> At
  k_reduce<<<2048 + 32 + 272, 256, 0, stream>>>(inputs, questions, A, TA, S, qs, w, u, At);
  // u = qs @ B
  k_u0<<<dim3(4, 4, 4), 256, 0, stream>>>(qs, B, u);
  for (int hop = 0; hop < NHOPS; ++hop) {
    k_w<<<dim3(5, 4, 4), 256, 0, stream>>>(At, u, w);
    k_sr<<<32, 1024, 0, stream>>>(S, w, p, r);
    k_o<<<dim3(4, 4, 4), 256, 0, stream>>>(C, TC, r, p, u);
  }
}

// Round 2
// 797.912 us; speedup vs baseline: 1.2714x; 1.2714x over previous
//
#include <hip/hip_runtime.h>

// ---------------------------------------------------------------------------
// MemN2N temporal layer, MEM=64 BATCH=32 L=64 E=1024 H=1024 HOPS=3, fp32.
//
// Algebra: with S[j,b,e] = sum_l inputs[j,b,l,e],
//   s[b,j] = sum_e S[j,b,e]*w[b,e] + w[b,1024+j],  w[b,:] = u[b,:] @ [A;TA]^T
//   o[b,h] = sum_e r[b,e]*C[e,h] + sum_j p[b,j]*TC[j,h],  r[b,e]=sum_j p_j S[j,b,e]
// so the 2048x1024x1024 GEMMs for m,c are never materialized. fp32 throughout
// keeps softmax-argmax stable (logits sigma~2048, near-one-hot).
//
// R1 -> R2: the per-hop kernels were latency-bound at 32-80 blocks. Rebuilt:
//  - k_s/k_pr replace the 32-block k_sr (512 / 128 blocks)
//  - k_u0/k_w/k_o: 256-320 blocks, split-k z=8, 4-batch register tile,
//    LDS-staged small vectors (kills per-lane uniform VMEM loads)
// ---------------------------------------------------------------------------

#define NMEM 64
#define NBATCH 32
#define NL 64
#define NE 1024
#define NH 1024
#define NEP 1088   /* NE + NMEM: A' = [A ; TA] */
#define NHOPS 3

// workspace float offsets (all multiples of 4 -> 16B aligned)
#define OFF_S   0u                          /* S: 2048 x 1024           */
#define OFF_QS  (2048u*1024u)               /* qs: 32 x 1024            */
#define OFF_W   (OFF_QS + 32u*1024u)        /* w: 32 x 1088             */
#define OFF_P   (OFF_W + 32u*1088u)         /* p: 32 x 64               */
#define OFF_R   (OFF_P + 32u*64u)           /* r: 32 x 1024             */
#define OFF_SV  (OFF_R + 32u*1024u)         /* s: 32 x 64               */
#define OFF_AT  (OFF_SV + 32u*64u)          /* At: 1024 x 1088 (A'^T)   */

// ---------------------------------------------------------------------------
// K_reduce: blocks 0..2047   : S[row,:] = sum_l inputs[row, l, :]  (512 MiB)
//           blocks 2048..2079: qs[b,:] = sum_l questions[b,l,:]; zero u, w
//           blocks 2080..2351: At[h,e'] = A'[e',h]  (LDS tile transpose)
// ---------------------------------------------------------------------------
__global__ __launch_bounds__(256) void k_reduce(
    const float* __restrict__ inputs, const float* __restrict__ questions,
    const float* __restrict__ A, const float* __restrict__ TA,
    float* __restrict__ S, float* __restrict__ qs,
    float* __restrict__ w, float* __restrict__ u, float* __restrict__ At) {
  const int blk = blockIdx.x, t = threadIdx.x;
  __shared__ float tile[64][65];

  if (blk < 2048) {
    const float4* base = (const float4*)(inputs + (size_t)blk * (NL * NE));
    float4 acc = make_float4(0.f, 0.f, 0.f, 0.f);
#pragma unroll 8
    for (int l = 0; l < NL; ++l) {
      float4 v = base[l * (NE / 4) + t];
      acc.x += v.x; acc.y += v.y; acc.z += v.z; acc.w += v.w;
    }
    ((float4*)(S + (size_t)blk * NE))[t] = acc;
  } else if (blk < 2080) {
    const int b = blk - 2048;
    const float4* base = (const float4*)(questions + (size_t)b * (NL * NE));
    float4 acc = make_float4(0.f, 0.f, 0.f, 0.f);
#pragma unroll 8
    for (int l = 0; l < NL; ++l) {
      float4 v = base[l * (NE / 4) + t];
      acc.x += v.x; acc.y += v.y; acc.z += v.z; acc.w += v.w;
    }
    ((float4*)(qs + (size_t)b * NE))[t] = acc;
    const float4 z = make_float4(0.f, 0.f, 0.f, 0.f);
    ((float4*)(u + (size_t)b * NH))[t] = z;
    ((float4*)(w + (size_t)b * NEP))[t] = z;
    if (t < 16) ((float4*)(w + (size_t)b * NEP))[256 + t] = z;
  } else {
    const int idx = blk - 2080;
    const int et = idx % 17;      // e'-tile of 64 (17*64 = 1088)
    const int ht = idx / 17;      // h-tile of 64  (16*64 = 1024)
    const int r0 = t >> 6, c = t & 63;
#pragma unroll
    for (int rr = r0; rr < 64; rr += 4) {
      const int e = et * 64 + rr, h = ht * 64 + c;
      tile[rr][c] = (e < NE) ? A[(size_t)e * NH + h] : TA[(size_t)(e - NE) * NH + h];
    }
    __syncthreads();
#pragma unroll
    for (int rr = r0; rr < 64; rr += 4) {
      const int h = ht * 64 + rr, e = et * 64 + c;
      At[(size_t)h * NEP + e] = tile[c][rr];
    }
  }
}

// ---------------------------------------------------------------------------
// K_u0: u[b,h] += sum_e qs[b,e]*B[e,h].  grid (4 h-tiles, 8 b-grp of 4,
// 8 e-chunks of 128), 256 thr.  qs chunk staged in LDS (broadcast reads).
// ---------------------------------------------------------------------------
__global__ __launch_bounds__(256) void k_u0(
    const float* __restrict__ qs, const float* __restrict__ B,
    float* __restrict__ u) {
  const int t = threadIdx.x;
  const int h = blockIdx.x * 256 + t;
  const int b0 = blockIdx.y * 4;
  const int e0 = blockIdx.z * 128;
  __shared__ float lq[4][128];
  for (int idx = t; idx < 512; idx += 256)
    lq[idx >> 7][idx & 127] = qs[(size_t)(b0 + (idx >> 7)) * NE + e0 + (idx & 127)];
  __syncthreads();
  float acc[4] = {0.f, 0.f, 0.f, 0.f};
#pragma unroll 8
  for (int i = 0; i < 128; ++i) {
    const float bv = B[(size_t)(e0 + i) * NH + h];
#pragma unroll
    for (int bb = 0; bb < 4; ++bb) acc[bb] += lq[bb][i] * bv;
  }
#pragma unroll
  for (int bb = 0; bb < 4; ++bb) atomicAdd(&u[(size_t)(b0 + bb) * NH + h], acc[bb]);
}

// ---------------------------------------------------------------------------
// K_w: w[b,e'] += sum_h u[b,h]*At[h,e'].  grid (5 ep-tiles, 8 b-grp of 4,
// 8 h-chunks of 128), 256 thr, guard ep<1088.  u chunk staged in LDS.
// ---------------------------------------------------------------------------
__global__ __launch_bounds__(256) void k_w(
    const float* __restrict__ At, const float* __restrict__ u,
    float* __restrict__ w) {
  const int t = threadIdx.x;
  const int ep = blockIdx.x * 256 + t;
  const int b0 = blockIdx.y * 4;
  const int h0 = blockIdx.z * 128;
  __shared__ float lu[4][128];
  for (int idx = t; idx < 512; idx += 256)
    lu[idx >> 7][idx & 127] = u[(size_t)(b0 + (idx >> 7)) * NH + h0 + (idx & 127)];
  __syncthreads();
  if (ep >= NEP) return;
  float acc[4] = {0.f, 0.f, 0.f, 0.f};
#pragma unroll 8
  for (int i = 0; i < 128; ++i) {
    const float av = At[(size_t)(h0 + i) * NEP + ep];
#pragma unroll
    for (int bb = 0; bb < 4; ++bb) acc[bb] += lu[bb][i] * av;
  }
#pragma unroll
  for (int bb = 0; bb < 4; ++bb) atomicAdd(&w[(size_t)(b0 + bb) * NEP + ep], acc[bb]);
}

// ---------------------------------------------------------------------------
// K_s: s[b,j] = S[j,b,:].w[b,:] + w[b,1024+j].  grid (16 j-grp, 32 b),
// 256 thr = 4 waves, one wave-dot (len 1024) per j.
// ---------------------------------------------------------------------------
__global__ __launch_bounds__(256) void k_s(
    const float* __restrict__ S, const float* __restrict__ w,
    float* __restrict__ sv) {
  const int lane = threadIdx.x & 63, wv = threadIdx.x >> 6;
  const int j = blockIdx.x * 4 + wv, b = blockIdx.y;
  const float4* S4 = (const float4*)(S + (size_t)(j * NBATCH + b) * NE);
  const float4* w4 = (const float4*)(w + (size_t)b * NEP);
  float acc = 0.f;
#pragma unroll
  for (int i = 0; i < 4; ++i) {
    const int slot = i * 64 + lane;
    float4 a = S4[slot], c = w4[slot];
    acc += a.x * c.x + a.y * c.y + a.z * c.z + a.w * c.w;
  }
#pragma unroll
  for (int off = 32; off > 0; off >>= 1) acc += __shfl_xor(acc, off, 64);
  if (lane == 0) sv[(size_t)b * NMEM + j] = acc + w[(size_t)b * NEP + NE + j];
}

// ---------------------------------------------------------------------------
// K_pr: softmax over s[b,:]; write p; r[b,e] = sum_j p_j S[j,b,e];
// re-zero w[b,:] for the next hop's atomic accumulation.
// grid (4 e-chunks of 256, 32 b), 256 thr.
// ---------------------------------------------------------------------------
__global__ __launch_bounds__(256) void k_pr(
    const float* __restrict__ S, const float* __restrict__ sv,
    float* __restrict__ p, float* __restrict__ r, float* __restrict__ w) {
  const int t = threadIdx.x;
  const int b = blockIdx.y, e0 = blockIdx.x * 256;
  __shared__ float lp[64];
  if (t < 64) {
    float s = sv[(size_t)b * NMEM + t];
    float m = s;
#pragma unroll
    for (int off = 32; off > 0; off >>= 1) m = fmaxf(m, __shfl_xor(m, off, 64));
    const float ex = __expf(s - m);
    float l = ex;
#pragma unroll
    for (int off = 32; off > 0; off >>= 1) l += __shfl_xor(l, off, 64);
    const float pv = ex / l;
    lp[t] = pv;
    if (blockIdx.x == 0) p[(size_t)b * NMEM + t] = pv;
  }
  __syncthreads();
  const int e = e0 + t;
  float acc = 0.f;
#pragma unroll 8
  for (int j = 0; j < NMEM; ++j)
    acc += lp[j] * S[(size_t)(j * NBATCH + b) * NE + e];
  r[(size_t)b * NE + e] = acc;
  // re-zero w row b (k_s already consumed it; k_pr runs after k_s)
  w[(size_t)b * NEP + e] = 0.f;
  if (blockIdx.x == 0 && t < 64) w[(size_t)b * NEP + NE + t] = 0.f;
}

// ---------------------------------------------------------------------------
// K_o: u[b,h] += sum_e r[b,e]*C[e,h] (+ sum_j p[b,j]*TC[j,h] on z==0).
// grid (4 h-tiles, 8 b-grp of 4, 8 e-chunks of 128), 256 thr, LDS-staged r/p.
// ---------------------------------------------------------------------------
__global__ __launch_bounds__(256) void k_o(
    const float* __restrict__ C, const float* __restrict__ TC,
    const float* __restrict__ r, const float* __restrict__ p,
    float* __restrict__ u) {
  const int t = threadIdx.x;
  const int h = blockIdx.x * 256 + t;
  const int b0 = blockIdx.y * 4;
  const int e0 = blockIdx.z * 128;
  __shared__ float lr[4][128];
  __shared__ float lp[4][64];
  for (int idx = t; idx < 512; idx += 256)
    lr[idx >> 7][idx & 127] = r[(size_t)(b0 + (idx >> 7)) * NE + e0 + (idx & 127)];
  if (blockIdx.z == 0 && t < 256) {
    const int bb = t >> 6, j = t & 63;
    lp[bb][j] = p[(size_t)(b0 + bb) * NMEM + j];
  }
  __syncthreads();
  float acc[4] = {0.f, 0.f, 0.f, 0.f};
#pragma unroll 8
  for (int i = 0; i < 128; ++i) {
    const float cv = C[(size_t)(e0 + i) * NH + h];
#pragma unroll
    for (int bb = 0; bb < 4; ++bb) acc[bb] += lr[bb][i] * cv;
  }
  if (blockIdx.z == 0) {
#pragma unroll 8
    for (int j = 0; j < NMEM; ++j) {
      const float tcv = TC[(size_t)j * NH + h];
#pragma unroll
      for (int bb = 0; bb < 4; ++bb) acc[bb] += lp[bb][j] * tcv;
    }
  }
#pragma unroll
  for (int bb = 0; bb < 4; ++bb) atomicAdd(&u[(size_t)(b0 + bb) * NH + h], acc[bb]);
}

// ---------------------------------------------------------------------------
extern "C" void kernel_launch(void* const* d_in, const int* in_sizes, int n_in,
                              void* d_out, int out_size, void* d_ws, size_t ws_size,
                              hipStream_t stream) {
  (void)in_sizes; (void)n_in; (void)out_size; (void)ws_size;
  const float* inputs    = (const float*)d_in[0];
  const float* questions = (const float*)d_in[1];
  const float* A         = (const float*)d_in[2];
  const float* C         = (const float*)d_in[3];
  const float* B         = (const float*)d_in[4];
  const float* TA        = (const float*)d_in[5];
  const float* TC        = (const float*)d_in[6];
  float* u  = (float*)d_out;
  float* ws = (float*)d_ws;
  float* S  = ws + OFF_S;
  float* qs = ws + OFF_QS;
  float* w  = ws + OFF_W;
  float* p  = ws + OFF_P;
  float* r  = ws + OFF_R;
  float* sv = ws + OFF_SV;
  float* At = ws + OFF_AT;

  k_reduce<<<2048 + 32 + 272, 256, 0, stream>>>(inputs, questions, A, TA, S, qs, w, u, At);
  k_u0<<<dim3(4, 8, 8), 256, 0, stream>>>(qs, B, u);
  for (int hop = 0; hop < NHOPS; ++hop) {
    k_w<<<dim3(5, 8, 8), 256, 0, stream>>>(At, u, w);
    k_s<<<dim3(16, 32), 256, 0, stream>>>(S, w, sv);
    k_pr<<<dim3(4, 32), 256, 0, stream>>>(S, sv, p, r, w);
    k_o<<<dim3(4, 8, 8), 256, 0, stream>>>(C, TC, r, p, u);
  }
}